// Round 8
// baseline (170.092 us; speedup 1.0000x reference)
//
#include <hip/hip_runtime.h>
#include <math.h>

#define NB 4
#define PP 256
#define CC 151
#define RR 51
#define CM 160                 // padded C (5 tiles of 32)
#define KS 64                  // split-K: 4 i's per block
#define NROW (NB*PP)           // 1024
#define MLB 10240              // halves per l per mat: 8 oct * 160 c * 8 j
#define TILE 5120              // halves per merged k16 step (both mats)

typedef _Float16 half8 __attribute__((ext_vector_type(8)));
typedef float floatx16 __attribute__((ext_vector_type(16)));

// ws layout (bytes): m1, m2, part
#define OFF_M1 ((size_t)0)
#define OFF_M2 (OFF_M1 + (size_t)CC*MLB*2)     // +3,092,480
#define OFF_PT (OFF_M2 + (size_t)CC*MLB*2)     // part: 64*1024*160*4 = 41.9 MB

__device__ __forceinline__ unsigned pk2(float a, float b) {
    union { _Float16 h[2]; unsigned u; } x;
    x.h[0] = (_Float16)a; x.h[1] = (_Float16)b;
    return x.u;
}

// ---------------------------------------------------------------------------
// K1: streaming M layout. m1[l][oct][c][j] = w_r*M[l][c][oct*8+j],
// m2[l][oct][c][j] = w_r*M[c][l][oct*8+j]; r=oct*8+j; w_0=0.5 else 0.25;
// zero for r>=51 or c>=151 (the zero r-rows make A's pad slots don't-care).
// ---------------------------------------------------------------------------
__global__ __launch_bounds__(256) void prep_kernel(const float* __restrict__ M,
                                                   _Float16* __restrict__ m1,
                                                   _Float16* __restrict__ m2,
                                                   float* __restrict__ out) {
    const int l = blockIdx.x;      // 0..150
    const int mat = blockIdx.y;    // 0,1
    if (l == 0 && mat == 0 && threadIdx.x == 0) *out = 0.f;
    _Float16* dst = (mat ? m2 : m1) + (size_t)l * MLB;
    for (int e = threadIdx.x; e < MLB; e += 256) {
        int oct = e / 1280;
        int rem = e - oct * 1280;
        int c = rem >> 3, j = rem & 7;
        int r = oct * 8 + j;
        float v = 0.f;
        if (r < RR && c < CC) {
            size_t src = ((size_t)(mat ? c * CC + l : l * CC + c)) * RR + r;
            v = (r == 0 ? 0.5f : 0.25f) * M[src];
        }
        dst[e] = (_Float16)v;
    }
}

// ---------------------------------------------------------------------------
// K2 (fused transpose+GEMM, 32x32x16 MFMA, LDS-staged coalesced A):
// part[ks][q][c] = sum_{i in chunk, r} rel[n,i,q,r]*w_r*M[lab_i,c,r]
//                                    + rel[n,q,i,r]*w_r*M[c,lab_i,r]
// Per i: A staged COALESCED (thread owns one (q, half-row); contiguous
// dword loads -> fp16 -> chunk-major LDS Ah[mat][kchunk][q], one
// ds_read_b128 per frag). Kills the 5x cacheline amplification of the old
// per-lane strided loads. B: contiguous global_load_lds tiles, triple-buf.
// Grid 512 = 4 img x 2 rowblk x 64 ks; 2 blocks/CU; LDS 62 KB.
// ---------------------------------------------------------------------------
__global__ __launch_bounds__(256, 2) void gemm_kernel(const float* __restrict__ rel,
                                                      const _Float16* __restrict__ m1,
                                                      const _Float16* __restrict__ m2,
                                                      const int* __restrict__ labels,
                                                      float* __restrict__ part) {
    __shared__ uint4 Ah[2][8][128];        // 32 KB: [mat][kchunk(8 halves)][qloc]
    __shared__ _Float16 Bt[3][TILE];       // 30 KB
    const int tid  = threadIdx.x;
    const int ks   = blockIdx.x & 63;
    const int rbk  = (blockIdx.x >> 6) & 1;
    const int n    = blockIdx.x >> 7;
    const int wave = tid >> 6, lane = tid & 63;
    const int m32  = lane & 31, kh = lane >> 5;
    const int i0   = ks * 4;
    const int q0   = rbk * 128;
    const int qloc = tid >> 1;             // staging row 0..127
    const int rg   = tid & 1;              // 0: r[0,32)  1: r[32,51)
    const int qglob = q0 + qloc;

    int labs[4];
    #pragma unroll
    for (int j = 0; j < 4; ++j) labs[j] = labels[n * PP + i0 + j];

    // zero-init the never-written junk slots (halves 52..55 of chunk 6, all
    // of chunk 7): garbage could be NaN and NaN*0 != 0.
    if (rg == 1) {
        #pragma unroll
        for (int m = 0; m < 2; ++m) {
            ((uint2*)&Ah[m][6][qloc])[1] = (uint2){0u, 0u};
            Ah[m][7][qloc] = (uint4){0u, 0u, 0u, 0u};
        }
    }

    floatx16 acc[5];
    #pragma unroll
    for (int ct = 0; ct < 5; ++ct)
        #pragma unroll
        for (int r2 = 0; r2 < 16; ++r2) acc[ct][r2] = 0.f;

    auto stageB = [&](int h, int buf) {
        const int il = h >> 2, t = h & 3;
        const size_t moff = (size_t)labs[il] * MLB + t * 2560;
        const _Float16* b1 = m1 + moff;
        const _Float16* b2 = m2 + moff;
        #pragma unroll
        for (int j = 0; j < 3; ++j) {
            int s = j * 256 + tid;
            if (s < 640) {
                const _Float16* g = (s < 320) ? b1 + (size_t)s * 8
                                              : b2 + (size_t)(s - 320) * 8;
                __builtin_amdgcn_global_load_lds(
                    (const __attribute__((address_space(1))) unsigned int*)g,
                    (__attribute__((address_space(3))) unsigned int*)(&Bt[buf][(size_t)s * 8]),
                    16, 0, 0);
            }
        }
    };

    // A-load registers for one i: per mat, rg0 holds 32 floats, rg1 19.
    float4 xa[8], xb[8];
    float ta[3], tb[3];

    auto issueA = [&](int il) {
        const int i = i0 + il;
        const float* s0 = rel + ((size_t)(n * PP + i) * PP + qglob) * RR + rg * 32;
        const float* s1 = rel + ((size_t)(n * PP + qglob) * PP + i) * RR + rg * 32;
        if (rg == 0) {
            #pragma unroll
            for (int j = 0; j < 8; ++j) {
                __builtin_memcpy(&xa[j], s0 + j * 4, 16);
                __builtin_memcpy(&xb[j], s1 + j * 4, 16);
            }
        } else {
            #pragma unroll
            for (int j = 0; j < 4; ++j) {
                __builtin_memcpy(&xa[j], s0 + j * 4, 16);
                __builtin_memcpy(&xb[j], s1 + j * 4, 16);
            }
            #pragma unroll
            for (int j = 0; j < 3; ++j) { ta[j] = s0[16 + j]; tb[j] = s1[16 + j]; }
        }
    };

    auto writeA = [&](int il) {
        const float z = ((i0 + il) == qglob) ? 0.f : 1.f;   // zero the diagonal
        #pragma unroll
        for (int m = 0; m < 2; ++m) {
            const float4* xs = m ? xb : xa;
            const float*  ts = m ? tb : ta;
            if (rg == 0) {
                #pragma unroll
                for (int ch = 0; ch < 4; ++ch) {
                    float4 u = xs[2 * ch], v = xs[2 * ch + 1];
                    uint4 w;
                    w.x = pk2(z * u.x, z * u.y); w.y = pk2(z * u.z, z * u.w);
                    w.z = pk2(z * v.x, z * v.y); w.w = pk2(z * v.z, z * v.w);
                    Ah[m][ch][qloc] = w;
                }
            } else {
                #pragma unroll
                for (int ch = 0; ch < 2; ++ch) {
                    float4 u = xs[2 * ch], v = xs[2 * ch + 1];
                    uint4 w;
                    w.x = pk2(z * u.x, z * u.y); w.y = pk2(z * u.z, z * u.w);
                    w.z = pk2(z * v.x, z * v.y); w.w = pk2(z * v.z, z * v.w);
                    Ah[m][4 + ch][qloc] = w;
                }
                uint2 w6;
                w6.x = pk2(z * ts[0], z * ts[1]);
                w6.y = pk2(z * ts[2], 0.f);
                ((uint2*)&Ah[m][6][qloc])[0] = w6;       // halves 48..51
            }
        }
    };

    issueA(0);
    stageB(0, 0); stageB(1, 1);

    for (int il = 0; il < 4; ++il) {
        if (il > 0) __syncthreads();       // all reads of Ah(il-1) complete
        writeA(il);
        if (il < 3) issueA(il + 1);        // coalesced loads for next i
        #pragma unroll
        for (int t = 0; t < 4; ++t) {
            const int h = il * 4 + t;
            __syncthreads();               // Ah writes + Bt[h] visible
            if (h + 2 < 16) stageB(h + 2, (h + 2) % 3);

            half8 a0 = *(const half8*)&Ah[0][t * 2 + kh][wave * 32 + m32];
            half8 a1 = *(const half8*)&Ah[1][t * 2 + kh][wave * 32 + m32];
            const _Float16* bb = &Bt[h % 3][(size_t)(kh * 160 + m32) * 8];
            #pragma unroll
            for (int ct = 0; ct < 5; ++ct) {
                half8 b0 = *(const half8*)(bb + ct * 256);
                half8 b1 = *(const half8*)(bb + 2560 + ct * 256);
                acc[ct] = __builtin_amdgcn_mfma_f32_32x32x16_f16(a0, b0, acc[ct], 0, 0, 0);
                acc[ct] = __builtin_amdgcn_mfma_f32_32x32x16_f16(a1, b1, acc[ct], 0, 0, 0);
            }
        }
    }

    // C/D 32x32 layout (m74/m101): col = m32, row = (reg&3)+8*(reg>>2)+4*kh
    float* pb = part + ((size_t)ks * NROW + n * PP + rbk * 128 + wave * 32) * CM;
    #pragma unroll
    for (int ct = 0; ct < 5; ++ct)
        #pragma unroll
        for (int reg = 0; reg < 16; ++reg) {
            int row = (reg & 3) + 8 * (reg >> 2) + 4 * kh;
            pb[(size_t)row * CM + ct * 32 + m32] = acc[ct][reg];
        }
}

// ---------------------------------------------------------------------------
// K3: theta[row][c] = sum_ks part; loss = lse(theta) - theta[lab]; mean.
// ---------------------------------------------------------------------------
__global__ __launch_bounds__(256) void reduce_loss_kernel(const float* __restrict__ part,
                                                          const int* __restrict__ labels,
                                                          float* __restrict__ out) {
    __shared__ float th[CM];
    const int row = blockIdx.x;
    const int t = threadIdx.x;
    if (t < CM) {
        float s = 0.f;
        #pragma unroll
        for (int ks = 0; ks < KS; ++ks)
            s += part[((size_t)ks * NROW + row) * CM + t];
        th[t] = s;
    }
    __syncthreads();
    if (t < 64) {
        float v0 = (t < CC)       ? th[t]       : -INFINITY;
        float v1 = (t + 64 < CC)  ? th[t + 64]  : -INFINITY;
        float v2 = (t + 128 < CC) ? th[t + 128] : -INFINITY;
        float m = fmaxf(v0, fmaxf(v1, v2));
        #pragma unroll
        for (int o = 32; o > 0; o >>= 1) m = fmaxf(m, __shfl_xor(m, o, 64));
        float s = 0.f;
        if (t < CC)       s += expf(v0 - m);
        if (t + 64 < CC)  s += expf(v1 - m);
        if (t + 128 < CC) s += expf(v2 - m);
        #pragma unroll
        for (int o = 32; o > 0; o >>= 1) s += __shfl_xor(s, o, 64);
        if (t == 0) {
            atomicAdd(out, (m + logf(s) - th[labels[row]]) * (1.0f / NROW));
        }
    }
}

// ---------------------------------------------------------------------------
extern "C" void kernel_launch(void* const* d_in, const int* in_sizes, int n_in,
                              void* d_out, int out_size, void* d_ws, size_t ws_size,
                              hipStream_t stream) {
    // inputs: 0=roi_scores (unused), 1=rel_scores, 2=relationship_mat,
    //         3=roi_labels, 4=num_images (fixed B=4)
    const float* rel    = (const float*)d_in[1];
    const float* relmat = (const float*)d_in[2];
    const int*   labels = (const int*)d_in[3];
    float* out = (float*)d_out;
    char* ws = (char*)d_ws;

    _Float16* m1 = (_Float16*)(ws + OFF_M1);
    _Float16* m2 = (_Float16*)(ws + OFF_M2);
    float*  part = (float*)(ws + OFF_PT);

    prep_kernel<<<dim3(CC, 2), 256, 0, stream>>>(relmat, m1, m2, out);
    gemm_kernel<<<NB * 2 * KS, 256, 0, stream>>>(rel, m1, m2, labels, part);
    reduce_loss_kernel<<<NROW, 256, 0, stream>>>(part, labels, out);
}